// Round 7
// baseline (18.689 us; speedup 1.0000x reference)
//
#include <hip/hip_runtime.h>

// Problem constants (match reference)
#define BATCH 32
#define NBOX 1024
#define NCLS 15
#define MAXM 300
#define CONF_THR 0.1f
#define KEEP_THR 0.2f
#define FEPS 1e-7f

// Sound decay bounds (f32): every decay-matrix element = exp(-(vv - ci2)/3)
// with vv = iou^2 in [0, 1.0f] and ci2 = cmax^2 in [0, 1.0f]
//   => decay in [exp(-1/3)-ulp, exp(1/3)+ulp] subset of [0.716530, 1.395613].
// conf >= C_HI: conf*decay >= 0.2794*0.716530 = 0.200199 > 0.2 -> keep.
// conf <= C_LO: conf*decay <= 0.1432*1.395613 = 0.199852 < 0.2 -> reject.
#define C_HI 0.2794f
#define C_LO 0.1432f

// ---------------------------------------------------------------------------
// Full reference ProbIoU chain (operand 1 = row i, operand 2 = column j),
// bit-exact op order, contraction off.
// ---------------------------------------------------------------------------
__device__ __forceinline__ float pair_iou(
    float x1, float y1, float a1, float b1, float c1, float det1,
    float x2, float y2, float a2, float b2, float c2, float det2) {
#pragma clang fp contract(off)
  float dx = x1 - x2;
  float dy = y1 - y2;
  float sa = a1 + a2;
  float sb = b1 + b2;
  float sc = c1 + c2;
  float denom = sa * sb - sc * sc + FEPS;
  float t1 = (sa * dy * dy + sb * dx * dx) / denom * 0.25f;
  float t2 = (sc * (-dx) * dy) / denom * 0.5f;
  float t3 = 0.5f * logf(denom / (4.0f * sqrtf(det1 * det2) + FEPS) + FEPS);
  float bd = t1 + t2 + t3;
  bd = fminf(fmaxf(bd, FEPS), 100.0f);
  float hd = sqrtf(1.0f - expf(-bd) + FEPS);
  return 1.0f - hd;
}

// ---------------------------------------------------------------------------
// Single fused kernel: one block per batch, 1024 threads (thread = row j).
//   1) conf/label via LDS-staged coalesced float4 score loads (4 chunks of
//      256 rows; stride-15 LDS reads are 2 lanes/bank = conflict-free).
//   2) ballot-count ambiguous rows (conf in (C_LO, C_HI)).
//   3) IF any ambiguous (never on bench data): LDS-staged bit-exact
//      Matrix-NMS to get decay for the ambiguous rows only.
//   4) keep decision -> stable ballot prefix-scan compaction -> outputs.
// ---------------------------------------------------------------------------
__global__ void __launch_bounds__(NBOX)
fused_kernel(const float* __restrict__ boxes,
             const float* __restrict__ scores,
             float* __restrict__ out) {
#pragma clang fp contract(off)
  const int b = blockIdx.x;
  const int j = threadIdx.x;  // 0..1023
  const int wave = j >> 6, lane = j & 63;
  const int base = b * NBOX;

  // ---- 1) conf / label via LDS-staged coalesced loads ----
  __shared__ float s_buf[256 * NCLS];  // 3840 floats = 15360 B per chunk
  float best = 0.0f;
  int lab = 0;
  {
    const size_t sb = (size_t)base * NCLS;
#pragma unroll
    for (int c = 0; c < 4; ++c) {
      const float4* src = (const float4*)(scores + sb + (size_t)c * 256 * NCLS);
      if (j < 960) ((float4*)s_buf)[j] = src[j];  // 960 float4 = 15360 B
      __syncthreads();
      if ((j >> 8) == c) {
        const float* row = s_buf + (j & 255) * NCLS;
        best = row[0];
        lab = 0;
#pragma unroll
        for (int k = 1; k < NCLS; ++k) {
          float s = row[k];
          if (s > best) { best = s; lab = k; }  // first-max = argmax semantics
        }
      }
      __syncthreads();
    }
  }
  float conf = (best < CONF_THR) ? 0.0f : best;
  int cls = (conf >= C_HI) ? 2 : ((conf > C_LO) ? 1 : 0);

  // ---- 2) ambiguous count ----
  __shared__ int s_ambw[16];
  __shared__ int s_amb;
  unsigned long long ambmask = __ballot(cls == 1);
  if (lane == 0) s_ambw[wave] = __popcll(ambmask);
  __syncthreads();
  if (j == 0) {
    int acc = 0;
#pragma unroll
    for (int w = 0; w < 16; ++w) acc += s_ambw[w];
    s_amb = acc;
  }
  __syncthreads();

  // ---- 3) rare exact fallback (bit-exact reference chain) ----
  __shared__ float s_dec[NBOX];
  if (s_amb > 0) {
    __shared__ float sX[NBOX], sY[NBOX], sA[NBOX], sB[NBOX], sC[NBOX], sD[NBOX];
    __shared__ float sCI2[NBOX];
    __shared__ float red[16];
    __shared__ float s_premin;
    __shared__ unsigned long long s_ambm[16];
    if (lane == 0) s_ambm[wave] = ambmask;

    const float* bx = boxes + (size_t)(base + j) * 5;
    {
      float w = bx[2], h = bx[3], r = bx[4];
      float a = w * w / 12.0f;
      float bb = h * h / 12.0f;
      float cs = cosf(r), sn = sinf(r);
      float va = a * cs * cs + bb * sn * sn;
      float vb = a * sn * sn + bb * cs * cs;
      float vc = (a - bb) * cs * sn;
      sX[j] = bx[0];
      sY[j] = bx[1];
      sA[j] = va;
      sB[j] = vb;
      sC[j] = vc;
      sD[j] = fmaxf(va * vb - vc * vc, 0.0f);
    }
    __syncthreads();

    // cmax for column j = max(0, max_{i<j} iou(i, j)); ci2 = cmax^2
    float m = 0.0f;
    for (int i = 0; i < j; ++i) {
      float v = pair_iou(sX[i], sY[i], sA[i], sB[i], sC[i], sD[i],
                         sX[j], sY[j], sA[j], sB[j], sC[j], sD[j]);
      m = fmaxf(m, v);
    }
    float c2 = m * m;
    sCI2[j] = c2;

    // premin = min_i ci2 (covers all far / i>=j candidates: -ci2_i <= vv-ci2_i)
    float pm = c2;
    for (int o = 32; o > 0; o >>= 1) pm = fminf(pm, __shfl_down(pm, o));
    if (lane == 0) red[wave] = pm;
    __syncthreads();
    if (j == 0) {
      float mm = red[0];
#pragma unroll
      for (int k = 1; k < 16; ++k) mm = fminf(mm, red[k]);
      s_premin = mm;
    }
    __syncthreads();

    // decay for each ambiguous column jj (block-uniform loop over set bits)
    for (int w = 0; w < 16; ++w) {
      unsigned long long wm = s_ambm[w];
      while (wm) {
        int jj = (w << 6) + __ffsll((long long)wm) - 1;
        wm &= wm - 1;
        float mm = -s_premin;
        if (j < jj) {
          float v = pair_iou(sX[j], sY[j], sA[j], sB[j], sC[j], sD[j],
                             sX[jj], sY[jj], sA[jj], sB[jj], sC[jj], sD[jj]);
          float vv = v * v;
          mm = fmaxf(mm, vv - sCI2[j]);
        }
        for (int o = 32; o > 0; o >>= 1) mm = fmaxf(mm, __shfl_down(mm, o));
        if (lane == 0) red[wave] = mm;
        __syncthreads();
        if (j == 0) {
          float mx = red[0];
#pragma unroll
          for (int k = 1; k < 16; ++k) mx = fmaxf(mx, red[k]);
          s_dec[jj] = expf((-mx) / 3.0f);
        }
        __syncthreads();
      }
    }
  }

  // ---- 4) keep -> stable compaction -> outputs ----
  bool keep;
  if (cls == 2) keep = true;
  else if (cls == 0) keep = false;
  else keep = (conf * s_dec[j]) > KEEP_THR;

  unsigned long long mask = __ballot(keep);
  int wprefix = __popcll(mask & ((1ull << lane) - 1ull));
  __shared__ int wsum[16];
  __shared__ int wbase[16];
  __shared__ int s_total;
  if (lane == 0) wsum[wave] = __popcll(mask);
  __syncthreads();
  if (j == 0) {
    int acc = 0;
#pragma unroll
    for (int w = 0; w < 16; ++w) { wbase[w] = acc; acc += wsum[w]; }
    s_total = acc;
  }
  __syncthreads();
  int num = min(s_total, MAXM);
  int pos = wbase[wave] + wprefix;

  float* o_num = out;
  float* o_box = out + BATCH;
  float* o_scr = out + BATCH + BATCH * MAXM * 5;
  float* o_cls = out + BATCH + BATCH * MAXM * 5 + BATCH * MAXM;

  if (j == 0) o_num[b] = (float)num;

  if (keep && pos < MAXM) {
    const float* src = boxes + (size_t)(base + j) * 5;
    float* dst = o_box + (size_t)(b * MAXM + pos) * 5;
#pragma unroll
    for (int k = 0; k < 5; ++k) dst[k] = src[k];
    o_scr[b * MAXM + pos] = conf;
    o_cls[b * MAXM + pos] = (float)lab;
  }
  if (j >= num && j < MAXM) {
    float* dst = o_box + (size_t)(b * MAXM + j) * 5;
#pragma unroll
    for (int k = 0; k < 5; ++k) dst[k] = -1.0f;
    o_scr[b * MAXM + j] = -1.0f;
    o_cls[b * MAXM + j] = -1.0f;
  }
}

// ---------------------------------------------------------------------------
extern "C" void kernel_launch(void* const* d_in, const int* in_sizes, int n_in,
                              void* d_out, int out_size, void* d_ws, size_t ws_size,
                              hipStream_t stream) {
  const float* boxes = (const float*)d_in[0];   // [B, N, 5]
  const float* scores = (const float*)d_in[1];  // [B, N, C]
  float* out = (float*)d_out;
  fused_kernel<<<BATCH, NBOX, 0, stream>>>(boxes, scores, out);
}

// Round 8
// 9.416 us; speedup vs baseline: 1.9849x; 1.9849x over previous
//
#include <hip/hip_runtime.h>

// Problem constants (match reference)
#define BATCH 32
#define NBOX 1024
#define NCLS 15
#define MAXM 300
#define CONF_THR 0.1f
#define KEEP_THR 0.2f
#define FEPS 1e-7f

// Sound decay bounds (f32): every decay-matrix element = exp(-(vv - ci2)/3)
// with vv = iou^2 in [0, 1.0f] (iou = 1 - sqrt(nonneg) <= 1.0f) and
// ci2 = cmax^2 in [0, 1.0f] (cmax has a 0 floor from the triu zeros).
//   => decay = min(elements) in [exp(-1/3)-ulp, exp(1/3)+ulp]
//           subset of [0.716530, 1.395613].
// conf >= C_HI: conf*decay >= 0.2794*0.716530 = 0.200199 > 0.2 -> keep.
// conf <= C_LO: conf*decay <= 0.1432*1.395613 = 0.199852 < 0.2 -> reject.
#define C_HI 0.2794f
#define C_LO 0.1432f

// ---------------------------------------------------------------------------
// Full reference ProbIoU chain (operand 1 = row i, operand 2 = column j),
// bit-exact op order, contraction off.
// ---------------------------------------------------------------------------
__device__ __forceinline__ float pair_iou(
    float x1, float y1, float a1, float b1, float c1, float det1,
    float x2, float y2, float a2, float b2, float c2, float det2) {
#pragma clang fp contract(off)
  float dx = x1 - x2;
  float dy = y1 - y2;
  float sa = a1 + a2;
  float sb = b1 + b2;
  float sc = c1 + c2;
  float denom = sa * sb - sc * sc + FEPS;
  float t1 = (sa * dy * dy + sb * dx * dx) / denom * 0.25f;
  float t2 = (sc * (-dx) * dy) / denom * 0.5f;
  float t3 = 0.5f * logf(denom / (4.0f * sqrtf(det1 * det2) + FEPS) + FEPS);
  float bd = t1 + t2 + t3;
  bd = fminf(fmaxf(bd, FEPS), 100.0f);
  float hd = sqrtf(1.0f - expf(-bd) + FEPS);
  return 1.0f - hd;
}

// ---------------------------------------------------------------------------
// Single fused kernel: one block per batch, 1024 threads (thread = row j).
//   1) conf/label from the 15 class scores (compiler clusters the adjacent
//      scalar loads into dwordx4 bundles — direct loads beat LDS staging,
//      measured round 6 vs 7: 9.4 vs 18.7 us).
//   2) ONE reduction round for both ballots: amb count + keep2 prefix bases.
//      Common path (amb == 0, always on bench data): keep == (cls == 2),
//      compaction uses the precomputed prefix -> 2 barriers total.
//   3) IF any ambiguous: LDS-staged bit-exact Matrix-NMS for decay of the
//      ambiguous rows, then a full re-ballot compaction (extra barriers).
//   4) stable ballot prefix-scan compaction -> batched outputs.
// ---------------------------------------------------------------------------
__global__ void __launch_bounds__(NBOX)
fused_kernel(const float* __restrict__ boxes,
             const float* __restrict__ scores,
             float* __restrict__ out) {
#pragma clang fp contract(off)
  const int b = blockIdx.x;
  const int j = threadIdx.x;  // 0..1023
  const int wave = j >> 6, lane = j & 63;
  const int base = b * NBOX;

  // ---- 1) conf / label ----
  const float* sc = scores + (size_t)(base + j) * NCLS;
  float best = sc[0];
  int lab = 0;
#pragma unroll
  for (int c = 1; c < NCLS; ++c) {
    float s = sc[c];
    if (s > best) { best = s; lab = c; }  // first-max = argmax semantics
  }
  float conf = (best < CONF_THR) ? 0.0f : best;
  int cls = (conf >= C_HI) ? 2 : ((conf > C_LO) ? 1 : 0);

  // ---- 2) single reduction round: amb count + keep2 prefix ----
  __shared__ int s_ambw[16];
  __shared__ int s_k2w[16];
  __shared__ int wbase[16];
  __shared__ int s_amb;
  __shared__ int s_total;
  unsigned long long ambmask = __ballot(cls == 1);
  unsigned long long k2mask = __ballot(cls == 2);
  if (lane == 0) {
    s_ambw[wave] = __popcll(ambmask);
    s_k2w[wave] = __popcll(k2mask);
  }
  __syncthreads();
  if (j == 0) {
    int acc = 0, amb = 0;
#pragma unroll
    for (int w = 0; w < 16; ++w) {
      wbase[w] = acc;
      acc += s_k2w[w];
      amb += s_ambw[w];
    }
    s_total = acc;
    s_amb = amb;
  }
  __syncthreads();

  bool keep;
  int pos;
  int num;

  if (s_amb == 0) {
    // ---- common path: keep == (cls == 2), prefix already computed ----
    keep = (cls == 2);
    pos = wbase[wave] + __popcll(k2mask & ((1ull << lane) - 1ull));
    num = min(s_total, MAXM);
  } else {
    // ---- 3) rare exact fallback (bit-exact reference chain) ----
    __shared__ float s_dec[NBOX];
    {
      __shared__ float sX[NBOX], sY[NBOX], sA[NBOX], sB[NBOX], sC[NBOX],
          sD[NBOX];
      __shared__ float sCI2[NBOX];
      __shared__ float red[16];
      __shared__ float s_premin;
      __shared__ unsigned long long s_ambm[16];
      if (lane == 0) s_ambm[wave] = ambmask;

      const float* bx = boxes + (size_t)(base + j) * 5;
      {
        float w = bx[2], h = bx[3], r = bx[4];
        float a = w * w / 12.0f;
        float bb = h * h / 12.0f;
        float cs = cosf(r), sn = sinf(r);
        float va = a * cs * cs + bb * sn * sn;
        float vb = a * sn * sn + bb * cs * cs;
        float vc = (a - bb) * cs * sn;
        sX[j] = bx[0];
        sY[j] = bx[1];
        sA[j] = va;
        sB[j] = vb;
        sC[j] = vc;
        sD[j] = fmaxf(va * vb - vc * vc, 0.0f);
      }
      __syncthreads();

      // cmax for column j = max(0, max_{i<j} iou(i, j)); ci2 = cmax^2
      float m = 0.0f;
      for (int i = 0; i < j; ++i) {
        float v = pair_iou(sX[i], sY[i], sA[i], sB[i], sC[i], sD[i],
                           sX[j], sY[j], sA[j], sB[j], sC[j], sD[j]);
        m = fmaxf(m, v);
      }
      float c2 = m * m;
      sCI2[j] = c2;

      // premin = min_i ci2 (covers all far / i>=j candidates)
      float pm = c2;
      for (int o = 32; o > 0; o >>= 1) pm = fminf(pm, __shfl_down(pm, o));
      if (lane == 0) red[wave] = pm;
      __syncthreads();
      if (j == 0) {
        float mm = red[0];
#pragma unroll
        for (int k = 1; k < 16; ++k) mm = fminf(mm, red[k]);
        s_premin = mm;
      }
      __syncthreads();

      // decay for each ambiguous column jj (block-uniform loop over set bits)
      for (int w = 0; w < 16; ++w) {
        unsigned long long wm = s_ambm[w];
        while (wm) {
          int jj = (w << 6) + __ffsll((long long)wm) - 1;
          wm &= wm - 1;
          float mm = -s_premin;
          if (j < jj) {
            float v = pair_iou(sX[j], sY[j], sA[j], sB[j], sC[j], sD[j],
                               sX[jj], sY[jj], sA[jj], sB[jj], sC[jj], sD[jj]);
            float vv = v * v;
            mm = fmaxf(mm, vv - sCI2[j]);
          }
          for (int o = 32; o > 0; o >>= 1) mm = fmaxf(mm, __shfl_down(mm, o));
          if (lane == 0) red[wave] = mm;
          __syncthreads();
          if (j == 0) {
            float mx = red[0];
#pragma unroll
            for (int k = 1; k < 16; ++k) mx = fmaxf(mx, red[k]);
            s_dec[jj] = expf((-mx) / 3.0f);
          }
          __syncthreads();
        }
      }
    }

    // full re-ballot compaction (keep for cls==1 now resolved via s_dec)
    if (cls == 2) keep = true;
    else if (cls == 0) keep = false;
    else keep = (conf * s_dec[j]) > KEEP_THR;

    unsigned long long mask = __ballot(keep);
    __syncthreads();  // wbase/s_total about to be overwritten
    if (lane == 0) s_k2w[wave] = __popcll(mask);
    __syncthreads();
    if (j == 0) {
      int acc = 0;
#pragma unroll
      for (int w = 0; w < 16; ++w) {
        wbase[w] = acc;
        acc += s_k2w[w];
      }
      s_total = acc;
    }
    __syncthreads();
    pos = wbase[wave] + __popcll(mask & ((1ull << lane) - 1ull));
    num = min(s_total, MAXM);
  }

  // ---- 4) outputs ----
  float* o_num = out;
  float* o_box = out + BATCH;
  float* o_scr = out + BATCH + BATCH * MAXM * 5;
  float* o_cls = out + BATCH + BATCH * MAXM * 5 + BATCH * MAXM;

  if (j == 0) o_num[b] = (float)num;

  if (keep && pos < MAXM) {
    const float* src = boxes + (size_t)(base + j) * 5;
    float* dst = o_box + (size_t)(b * MAXM + pos) * 5;
#pragma unroll
    for (int k = 0; k < 5; ++k) dst[k] = src[k];
    o_scr[b * MAXM + pos] = conf;
    o_cls[b * MAXM + pos] = (float)lab;
  }
  if (j >= num && j < MAXM) {
    float* dst = o_box + (size_t)(b * MAXM + j) * 5;
#pragma unroll
    for (int k = 0; k < 5; ++k) dst[k] = -1.0f;
    o_scr[b * MAXM + j] = -1.0f;
    o_cls[b * MAXM + j] = -1.0f;
  }
}

// ---------------------------------------------------------------------------
extern "C" void kernel_launch(void* const* d_in, const int* in_sizes, int n_in,
                              void* d_out, int out_size, void* d_ws, size_t ws_size,
                              hipStream_t stream) {
  const float* boxes = (const float*)d_in[0];   // [B, N, 5]
  const float* scores = (const float*)d_in[1];  // [B, N, C]
  float* out = (float*)d_out;
  fused_kernel<<<BATCH, NBOX, 0, stream>>>(boxes, scores, out);
}